// Round 7
// baseline (430.811 us; speedup 1.0000x reference)
//
#include <hip/hip_runtime.h>
#include <math.h>

// ws layout (floats):
//   accS [80] @0, accQ [1200] @80, accQS [6000] @1280, ctr(int) @7280,
//   SHL(u16) @7296: 10400 x 640; QHL after: 30000 x 640.

#define EXP_C (-0.25f * 1.44269504088896340736f)  // 2*(-0.125)*log2(e)

typedef __attribute__((ext_vector_type(8))) short bf16x8_t;
typedef __attribute__((ext_vector_type(4))) float f32x4_t;
typedef unsigned short u16;

#define GLOAD_LDS16(g, l)                                 \
  __builtin_amdgcn_global_load_lds(                       \
      (const __attribute__((address_space(1))) void*)(g), \
      (__attribute__((address_space(3))) void*)(l), 16, 0, 0)

__device__ __forceinline__ u16 f2bf(float f) {
  unsigned int u = __float_as_uint(f);
  unsigned int r = (u + 0x7fffu + ((u >> 16) & 1u)) >> 16;
  return (u16)r;
}

// sum_a exp(-a*d2), a=0.125*2^k k=0..4, d2 = max(2-2g,0)
__device__ __forceinline__ float mgauss(float g) {
  float h = fmaxf(1.f - g, 0.f);
  float e1 = exp2f(h * EXP_C);
  float e2 = e1 * e1, e4 = e2 * e2, e8 = e4 * e4, e16 = e8 * e8;
  return e1 + e2 + e4 + e8 + e16;
}

__device__ __forceinline__ float wred(float v) {
#pragma unroll
  for (int m = 1; m < 64; m <<= 1) v += __shfl_xor(v, m, 64);
  return v;
}

// fused: zero accumulators+counter + center/l2norm/bf16 cast for S and Q
__global__ void prep_kernel(const float* __restrict__ S,
                            const float* __restrict__ Q,
                            u16* __restrict__ SHL, u16* __restrict__ QHL,
                            float* __restrict__ accz) {
  int bid = blockIdx.x, tid = threadIdx.x;
  if (bid < 29) {
    int z = bid * 256 + tid;
    if (z < 7296) accz[z] = 0.f;
  }
  int wid = (bid << 2) | (tid >> 6);
  int lane = tid & 63;
  const float* src;
  u16* dst;
  if (wid < 10400) {
    src = S + (size_t)wid * 640;
    dst = SHL + (size_t)wid * 640;
  } else {
    int w2 = wid - 10400;
    src = Q + (size_t)w2 * 640;
    dst = QHL + (size_t)w2 * 640;
  }
  const float4* s4 = (const float4*)src;
  float4 a = s4[lane];
  float4 b = s4[lane + 64];
  float4 c = make_float4(0.f, 0.f, 0.f, 0.f);
  if (lane < 32) c = s4[lane + 128];
  float s = a.x + a.y + a.z + a.w + b.x + b.y + b.z + b.w + c.x + c.y + c.z +
            c.w;
  float ss = a.x * a.x + a.y * a.y + a.z * a.z + a.w * a.w + b.x * b.x +
             b.y * b.y + b.z * b.z + b.w * b.w + c.x * c.x + c.y * c.y +
             c.z * c.z + c.w * c.w;
#pragma unroll
  for (int m = 1; m < 64; m <<= 1) {
    s += __shfl_xor(s, m, 64);
    ss += __shfl_xor(ss, m, 64);
  }
  float mean = s * (1.f / 640.f);
  float inv = 1.f / sqrtf(fmaxf(ss - s * s * (1.f / 640.f), 0.f) + 1e-12f);
  ushort4* d4 = (ushort4*)dst;
  d4[lane] = make_ushort4(f2bf((a.x - mean) * inv), f2bf((a.y - mean) * inv),
                          f2bf((a.z - mean) * inv), f2bf((a.w - mean) * inv));
  d4[lane + 64] =
      make_ushort4(f2bf((b.x - mean) * inv), f2bf((b.y - mean) * inv),
                   f2bf((b.z - mean) * inv), f2bf((b.w - mean) * inv));
  if (lane < 32)
    d4[lane + 128] =
        make_ushort4(f2bf((c.x - mean) * inv), f2bf((c.y - mean) * inv),
                     f2bf((c.z - mean) * inv), f2bf((c.w - mean) * inv));
}

// 880 blocks x 512 threads. ids 0..383: cross 256x256 (8 waves of 128x64);
// 384..639: selfS 128x128; 640..879: selfQ 128x128 (waves of 64x32).
// 2-phase double-buffered global_load_lds, XOR-swizzled LDS, K=640.
// Last block (device counter) computes the final MMD output.
__global__ __launch_bounds__(512, 2) void mmd_kernel(
    const u16* __restrict__ SHL, const u16* __restrict__ QHL,
    float* __restrict__ accS, float* __restrict__ accQ,
    float* __restrict__ accQS, int* __restrict__ ctr,
    float* __restrict__ out) {
  __shared__ __align__(16) u16 sA[2][256 * 64];
  __shared__ __align__(16) u16 sB[2][256 * 64];
  __shared__ int lastflag;
  const int bid = blockIdx.x;
  const int id = (bid & 7) * 110 + (bid >> 3);  // XCD swizzle (880 = 8*110)
  const int tid = threadIdx.x;
  const int w = tid >> 6, l = tid & 63;
  const int lr = l & 15, lk8 = (l >> 4) * 8;

  if (id < 384) {
    // ---- mode 0: cross, 256x256 tile ----
    const int gb = id / 24;
    const int r = id % 24;
    const int i0 = (r % 3) * 256, j0 = (r / 3) * 256;
    const u16* pX = SHL + (size_t)gb * 650 * 640;
    const u16* pY = QHL + (size_t)gb * 1875 * 640;
    const u16 *gA[4], *gB[4];
#pragma unroll
    for (int i = 0; i < 4; ++i) {
      int s = (w * 4 + i) * 64 + l;
      int rw = s >> 3;
      int c16 = ((s & 7) ^ (rw & 7)) * 8;  // inverse-swizzled source granule
      int vi = i0 + rw;
      vi = vi < 650 ? vi : 649;
      gA[i] = pX + (size_t)vi * 640 + c16;
      int vj = j0 + rw;
      vj = vj < 1875 ? vj : 1874;
      gB[i] = pY + (size_t)vj * 640 + c16;
    }
    const int R0 = (w >> 2) * 128, C0 = (w & 3) * 64;
    f32x4_t av[8][4];
#pragma unroll
    for (int i = 0; i < 8; ++i)
#pragma unroll
      for (int j = 0; j < 4; ++j)
#pragma unroll
        for (int q = 0; q < 4; ++q) av[i][j][q] = 0.f;

#define STG0(bb, c)                                         \
  {                                                         \
    int kb = (c) * 64;                                      \
    _Pragma("unroll") for (int i = 0; i < 4; ++i) {         \
      GLOAD_LDS16(gA[i] + kb, &sA[bb][(w * 4 + i) * 512]);  \
      GLOAD_LDS16(gB[i] + kb, &sB[bb][(w * 4 + i) * 512]);  \
    }                                                       \
  }
#define CMP0(bb)                                                              \
  {                                                                           \
    _Pragma("unroll") for (int ks = 0; ks < 2; ++ks) {                        \
      bf16x8_t af[8], bfv[4];                                                 \
      int kk = ks * 32 + lk8;                                                 \
      _Pragma("unroll") for (int t = 0; t < 8; ++t) {                         \
        int rr = R0 + t * 16 + lr;                                            \
        af[t] = *(const bf16x8_t*)&sA[bb][rr * 64 + (kk ^ ((rr & 7) << 3))];  \
      }                                                                       \
      _Pragma("unroll") for (int t = 0; t < 4; ++t) {                         \
        int cc = C0 + t * 16 + lr;                                            \
        bfv[t] = *(const bf16x8_t*)&sB[bb][cc * 64 + (kk ^ ((cc & 7) << 3))]; \
      }                                                                       \
      _Pragma("unroll") for (int i = 0; i < 8; ++i)                           \
          _Pragma("unroll") for (int j = 0; j < 4; ++j) av[i][j] =            \
          __builtin_amdgcn_mfma_f32_16x16x32_bf16(af[i], bfv[j], av[i][j], 0, \
                                                  0, 0);                      \
    }                                                                         \
  }
    STG0(0, 0);
    __syncthreads();
    for (int c = 0; c < 10; ++c) {
      if (c < 9) STG0((c + 1) & 1, c + 1);
      CMP0(c & 1);
      __syncthreads();
    }
#undef STG0
#undef CMP0
    // epilogue
    const int cbi = (i0 + R0) / 130;
    const int cbj = (j0 + C0) / 25;
    int gcv[4], cjr[4];
    bool cvv[4];
#pragma unroll
    for (int j = 0; j < 4; ++j) {
      gcv[j] = j0 + C0 + j * 16 + lr;
      cvv[j] = gcv[j] < 1875;
      cjr[j] = gcv[j] / 25 - cbj;
    }
    float ce[2][4] = {{0.f, 0.f, 0.f, 0.f}, {0.f, 0.f, 0.f, 0.f}};
#pragma unroll
    for (int i = 0; i < 8; ++i)
#pragma unroll
      for (int rr = 0; rr < 4; ++rr) {
        int gr = i0 + R0 + i * 16 + (l >> 4) * 4 + rr;
        bool rv = gr < 650;
        bool ra = (gr / 130) == cbi;
#pragma unroll
        for (int j = 0; j < 4; ++j) {
          float kv = mgauss(av[i][j][rr]);
          kv = (rv && cvv[j]) ? kv : 0.f;
          float k0 = ra ? kv : 0.f;
          ce[0][j] += k0;
          ce[1][j] += kv - k0;
        }
      }
#pragma unroll
    for (int a = 0; a < 2; ++a)
#pragma unroll
      for (int bq = 0; bq < 4; ++bq) {
        float t = 0.f;
#pragma unroll
        for (int j = 0; j < 4; ++j) t += (cjr[j] == bq) ? ce[a][j] : 0.f;
        t = wred(t);
        if (l == 0) {
          int ci = cbi + a, cj = cbj + bq;
          if (ci < 5 && cj < 75) atomicAdd(&accQS[gb * 375 + cj * 5 + ci], t);
        }
      }
  } else {
    // ---- modes 1/2: self terms, 128x128 tile, wave 64x32 ----
    int mode, gb, i0, j0, nx;
    const u16* pX;
    if (id < 640) {
      mode = 1;
      int t = id - 384;
      gb = t >> 4;
      int p = t & 15;
      int ti, tj;
      if (p < 4) {
        ti = p >> 1;
        tj = p & 1;
      } else {
        int q = (p - 4) / 3, r3 = (p - 4) % 3;
        ti = (r3 == 0) ? q + 1 : q + 2;
        tj = (r3 == 1) ? q + 1 : q + 2;
      }
      i0 = ti * 128;
      j0 = tj * 128;
      pX = SHL + (size_t)gb * 650 * 640;
      nx = 650;
    } else {
      mode = 2;
      gb = id - 640;
      i0 = 0;
      j0 = 0;
      pX = QHL + (size_t)gb * 125 * 640;
      nx = 125;
    }
    const u16 *gA[2], *gB[2];
#pragma unroll
    for (int i = 0; i < 2; ++i) {
      int s = i * 512 + tid;
      int rw = s >> 3;
      int c16 = ((s & 7) ^ (rw & 7)) * 8;
      int vi = i0 + rw;
      vi = vi < nx ? vi : nx - 1;
      gA[i] = pX + (size_t)vi * 640 + c16;
      int vj = j0 + rw;
      vj = vj < nx ? vj : nx - 1;
      gB[i] = pX + (size_t)vj * 640 + c16;
    }
    const int R0 = (w >> 2) * 64, C0 = (w & 3) * 32;
    f32x4_t av[4][2];
#pragma unroll
    for (int i = 0; i < 4; ++i)
#pragma unroll
      for (int j = 0; j < 2; ++j)
#pragma unroll
        for (int q = 0; q < 4; ++q) av[i][j][q] = 0.f;

#define STG1(bb, c)                                        \
  {                                                        \
    int kb = (c) * 64;                                     \
    _Pragma("unroll") for (int i = 0; i < 2; ++i) {        \
      GLOAD_LDS16(gA[i] + kb, &sA[bb][(i * 8 + w) * 512]); \
      GLOAD_LDS16(gB[i] + kb, &sB[bb][(i * 8 + w) * 512]); \
    }                                                      \
  }
#define CMP1(bb)                                                              \
  {                                                                           \
    _Pragma("unroll") for (int ks = 0; ks < 2; ++ks) {                        \
      bf16x8_t af[4], bfv[2];                                                 \
      int kk = ks * 32 + lk8;                                                 \
      _Pragma("unroll") for (int t = 0; t < 4; ++t) {                         \
        int rr = R0 + t * 16 + lr;                                            \
        af[t] = *(const bf16x8_t*)&sA[bb][rr * 64 + (kk ^ ((rr & 7) << 3))];  \
      }                                                                       \
      _Pragma("unroll") for (int t = 0; t < 2; ++t) {                         \
        int cc = C0 + t * 16 + lr;                                            \
        bfv[t] = *(const bf16x8_t*)&sB[bb][cc * 64 + (kk ^ ((cc & 7) << 3))]; \
      }                                                                       \
      _Pragma("unroll") for (int i = 0; i < 4; ++i)                           \
          _Pragma("unroll") for (int j = 0; j < 2; ++j) av[i][j] =            \
          __builtin_amdgcn_mfma_f32_16x16x32_bf16(af[i], bfv[j], av[i][j], 0, \
                                                  0, 0);                      \
    }                                                                         \
  }
    STG1(0, 0);
    __syncthreads();
    for (int c = 0; c < 10; ++c) {
      if (c < 9) STG1((c + 1) & 1, c + 1);
      CMP1(c & 1);
      __syncthreads();
    }
#undef STG1
#undef CMP1
    int gcv[2], ccv[2];
    bool cvv[2];
#pragma unroll
    for (int j = 0; j < 2; ++j) {
      gcv[j] = j0 + C0 + j * 16 + lr;
      cvv[j] = gcv[j] < nx;
    }
    if (mode == 1) {
      const int cbi = (i0 + R0) / 130;
#pragma unroll
      for (int j = 0; j < 2; ++j) ccv[j] = gcv[j] / 130;
      float ce[2] = {0.f, 0.f};
#pragma unroll
      for (int i = 0; i < 4; ++i)
#pragma unroll
        for (int rr = 0; rr < 4; ++rr) {
          int gr = i0 + R0 + i * 16 + (l >> 4) * 4 + rr;
          bool rv = gr < 650;
          int rc = gr / 130;
          bool ra = rc == cbi;
#pragma unroll
          for (int j = 0; j < 2; ++j) {
            float kv = mgauss(av[i][j][rr]);
            bool val = rv && cvv[j] && (ccv[j] == rc) && (gr != gcv[j]);
            kv = val ? kv : 0.f;
            float k0 = ra ? kv : 0.f;
            ce[0] += k0;
            ce[1] += kv - k0;
          }
        }
#pragma unroll
      for (int a = 0; a < 2; ++a) {
        float t = wred(ce[a]);
        if (l == 0) {
          int ci = cbi + a;
          if (ci < 5) atomicAdd(&accS[gb * 5 + ci], t);
        }
      }
    } else {
      const int cbi = R0 / 25;
#pragma unroll
      for (int j = 0; j < 2; ++j) ccv[j] = gcv[j] / 25;
      float ce[4] = {0.f, 0.f, 0.f, 0.f};
#pragma unroll
      for (int i = 0; i < 4; ++i)
#pragma unroll
        for (int rr = 0; rr < 4; ++rr) {
          int gr = R0 + i * 16 + (l >> 4) * 4 + rr;
          bool rv = gr < 125;
          int rc = gr / 25;
          int ar = rc - cbi;
#pragma unroll
          for (int j = 0; j < 2; ++j) {
            float kv = mgauss(av[i][j][rr]);
            bool val = rv && cvv[j] && (ccv[j] == rc) && (gr != gcv[j]);
            kv = val ? kv : 0.f;
#pragma unroll
            for (int a = 0; a < 4; ++a) ce[a] += (ar == a) ? kv : 0.f;
          }
        }
#pragma unroll
      for (int a = 0; a < 4; ++a) {
        float t = wred(ce[a]);
        if (l == 0) {
          int ci = cbi + a;
          if (ci < 5) atomicAdd(&accQ[gb * 5 + ci], t);
        }
      }
    }
  }

  // ---- fused finalize: last block computes the output ----
  __threadfence();
  if (tid == 0) {
    int old = __hip_atomic_fetch_add(ctr, 1, __ATOMIC_ACQ_REL,
                                     __HIP_MEMORY_SCOPE_AGENT);
    lastflag = (old == 879) ? 1 : 0;
  }
  __syncthreads();
  if (lastflag) {
    for (int k = tid; k < 6000; k += 512) {
      int w5 = k % 5, bq = k / 5, b = k / 375;
      float aS = __hip_atomic_load(&accS[b * 5 + w5], __ATOMIC_RELAXED,
                                   __HIP_MEMORY_SCOPE_AGENT);
      float aQ = __hip_atomic_load(&accQ[bq], __ATOMIC_RELAXED,
                                   __HIP_MEMORY_SCOPE_AGENT);
      float aQS = __hip_atomic_load(&accQS[k], __ATOMIC_RELAXED,
                                    __HIP_MEMORY_SCOPE_AGENT);
      out[k] = aS * (1.f / (130.f * 129.f)) + aQ * (1.f / (25.f * 24.f)) -
               aQS * (2.f / (130.f * 25.f));
    }
  }
}

extern "C" void kernel_launch(void* const* d_in, const int* in_sizes, int n_in,
                              void* d_out, int out_size, void* d_ws,
                              size_t ws_size, hipStream_t stream) {
  const float* S = (const float*)d_in[0];  // [16,5,130,640]
  const float* Q = (const float*)d_in[1];  // [16,75,25,640]
  float* ws = (float*)d_ws;
  float* accS = ws + 0;
  float* accQ = ws + 80;
  float* accQS = ws + 1280;
  int* ctr = (int*)(ws + 7280);
  u16* SHL = (u16*)(ws + 7296);
  u16* QHL = SHL + (size_t)10400 * 640;
  float* out = (float*)d_out;

  prep_kernel<<<10100, 256, 0, stream>>>(S, Q, SHL, QHL, ws);
  mmd_kernel<<<880, 512, 0, stream>>>(SHL, QHL, accS, accQ, accQS, ctr, out);
}